// Round 3
// baseline (238.887 us; speedup 1.0000x reference)
//
#include <hip/hip_runtime.h>
#include <hip/hip_cooperative_groups.h>

namespace cg = cooperative_groups;
typedef unsigned int u32;

#define HALF_T 2097152u   // 2048*2048/2
#define NPX 2048
#define NPOOL_BLOCKS 4096
#define COOP_BLOCKS 1024

// ---------------- threefry2x32 (JAX-exact, 20 rounds) ----------------
__host__ __device__ inline void tf2x32(u32 k0, u32 k1, u32& x0, u32& x1) {
  const u32 ks2 = k0 ^ k1 ^ 0x1BD11BDAu;
  x0 += k0; x1 += k1;
#define TFR(r) { x0 += x1; x1 = (x1 << (r)) | (x1 >> (32 - (r))); x1 ^= x0; }
  TFR(13) TFR(15) TFR(26) TFR(6)
  x0 += k1;  x1 += ks2 + 1u;
  TFR(17) TFR(29) TFR(16) TFR(24)
  x0 += ks2; x1 += k0 + 2u;
  TFR(13) TFR(15) TFR(26) TFR(6)
  x0 += k0;  x1 += k1 + 3u;
  TFR(17) TFR(29) TFR(16) TFR(24)
  x0 += k1;  x1 += ks2 + 4u;
  TFR(13) TFR(15) TFR(26) TFR(6)
  x0 += ks2; x1 += k0 + 5u;
#undef TFR
}

__device__ inline u32 pbits(u32 k0, u32 k1, u32 t) {
  u32 x0 = 0u, x1 = t;
  tf2x32(k0, k1, x0, x1);
  return x0 ^ x1;
}

__device__ inline float bits_to_uniform(u32 bits) {
  return __uint_as_float((bits >> 9) | 0x3F800000u) - 1.0f;
}

// -------- adjacency evaluation from an LDS tile --------
// s[lc][lr] = dn[i = c0-1+lc][j = r0-1+lr]; thread center at lc=tx+1, lr=ty+1.
__device__ inline bool adj_eval(const float s[34][35], int tx, int ty,
                                int c, int rr, float thr) {
  const float ctr = s[tx+1][ty+1];
  const bool cge1 = (c  >= 1),    cle = (c  <= NPX - 2);
  const bool rge1 = (rr >= 1),    rle = (rr <= NPX - 2);
  bool a = false;
  if (cge1 && rge1)                    a |= (fabsf(s[tx  ][ty  ] - ctr) <= thr); // d[i-1,j-1]
  if (cge1 && cle && rge1 && rle)      a |= (fabsf(s[tx+2][ty  ] - ctr) <= thr); // d[i+1,j-1]
  if (cge1 && rle)                     a |= (fabsf(s[tx  ][ty+2] - ctr) <= thr); // d[i-1,j+1]
  if (cle  && rle)                     a |= (fabsf(s[tx+2][ty+2] - ctr) <= thr); // d[i+1,j+1]
  return a;
}

// ==================== cooperative fused kernel ====================
// grid 1024 x 256, __launch_bounds__(256,4) -> 4 blocks/CU x 256 CU = 1024 co-resident.
__global__ __launch_bounds__(256, 4) void k_all(const float* __restrict__ coarse,
                                                float2* __restrict__ dn2,
                                                float* __restrict__ pmin,
                                                float* __restrict__ pmax,
                                                int* __restrict__ out,
                                                u32 kn0, u32 kn1, u32 kd0, u32 kd1) {
  const int tid = threadIdx.x;
  const float* dn = (const float*)dn2;

  // ---- phase 1: maxpool + noise -> dn, track block min/max ----
  float lmin = INFINITY, lmax = -INFINITY;
  for (u32 g = blockIdx.x * 256u + (u32)tid; g < 1048576u; g += COOP_BLOCKS * 256u) {
    const int i  = g >> 10;
    const int jj = g & 1023;
    const float4* r0 = (const float4*)(coarse + (size_t)(2*i       ) * 4096);
    const float4* r1 = (const float4*)(coarse + (size_t)(2*i + 1   ) * 4096);
    const float4* r2 = (const float4*)(coarse + (size_t)(2*i + 2048) * 4096);
    const float4* r3 = (const float4*)(coarse + (size_t)(2*i + 2049) * 4096);
    const float4 a = r0[jj], b = r1[jj], c = r2[jj], d = r3[jj];

    const float p0a = fmaxf(fmaxf(a.x, a.y), fmaxf(b.x, b.y));
    const float p0b = fmaxf(fmaxf(a.z, a.w), fmaxf(b.z, b.w));
    const float p1a = fmaxf(fmaxf(c.x, c.y), fmaxf(d.x, d.y));
    const float p1b = fmaxf(fmaxf(c.z, c.w), fmaxf(d.z, d.w));

    lmin = fminf(lmin, fminf(fminf(p0a, p0b), fminf(p1a, p1b)));
    lmax = fmaxf(lmax, fmaxf(fmaxf(p0a, p0b), fmaxf(p1a, p1b)));

    const u32 t0 = (u32)i * 2048u + 2u * (u32)jj;
    const u32 t2 = t0 + HALF_T;
    dn2[(size_t)i * 1024 + jj] =
        make_float2(p0a + bits_to_uniform(pbits(kn0, kn1, t0)),
                    p0b + bits_to_uniform(pbits(kn0, kn1, t0 + 1u)));
    dn2[(size_t)(i + 1024) * 1024 + jj] =
        make_float2(p1a + bits_to_uniform(pbits(kn0, kn1, t2)),
                    p1b + bits_to_uniform(pbits(kn0, kn1, t2 + 1u)));
  }
  for (int off = 32; off > 0; off >>= 1) {
    lmin = fminf(lmin, __shfl_down(lmin, off, 64));
    lmax = fmaxf(lmax, __shfl_down(lmax, off, 64));
  }
  __shared__ float smin[4], smax[4];
  const int lane = tid & 63, wv = tid >> 6;
  if (lane == 0) { smin[wv] = lmin; smax[wv] = lmax; }
  __syncthreads();
  if (tid == 0) {
    pmin[blockIdx.x] = fminf(fminf(smin[0], smin[1]), fminf(smin[2], smin[3]));
    pmax[blockIdx.x] = fmaxf(fmaxf(smax[0], smax[1]), fmaxf(smax[2], smax[3]));
  }

  cg::this_grid().sync();

  // ---- phase 2: redundant per-block thr reduce (1024 partials, L2-resident) ----
  __shared__ float s2min[4], s2max[4], sthr;
  float m2 = INFINITY, M2 = -INFINITY;
#pragma unroll
  for (int k = 0; k < COOP_BLOCKS; k += 256) {
    m2 = fminf(m2, pmin[tid + k]);
    M2 = fmaxf(M2, pmax[tid + k]);
  }
  for (int off = 32; off > 0; off >>= 1) {
    m2 = fminf(m2, __shfl_down(m2, off, 64));
    M2 = fmaxf(M2, __shfl_down(M2, off, 64));
  }
  if (lane == 0) { s2min[wv] = m2; s2max[wv] = M2; }
  __syncthreads();
  if (tid == 0) {
    const float gmin = fminf(fminf(s2min[0], s2min[1]), fminf(s2min[2], s2min[3]));
    const float gmax = fmaxf(fmaxf(s2max[0], s2max[1]), fmaxf(s2max[2], s2max[3]));
    sthr = (gmax - gmin) / 2048.0f;
  }
  __syncthreads();
  const float thr = sthr;

  // ---- phase 3: adjacency + dropout over 4096 32x32 tiles, 4 per block ----
  __shared__ float s[34][35];
  const int tx = tid & 31, ty0 = tid >> 5;
  for (int T = blockIdx.x; T < 4096; T += COOP_BLOCKS) {
    const int c0 = (T & 63) * 32;
    const int r0 = (T >> 6) * 32;
    __syncthreads();   // previous tile's readers done before overwrite
    for (int idx = tid; idx < 34 * 34; idx += 256) {
      const int lc = idx / 34, lr = idx - lc * 34;
      const int c = c0 - 1 + lc;
      const int r = r0 - 1 + lr;
      float v = 0.f;
      if ((unsigned)c < (unsigned)NPX && (unsigned)r < (unsigned)NPX)
        v = dn[(size_t)c * NPX + r];
      s[lc][lr] = v;
    }
    __syncthreads();
#pragma unroll
    for (int m = 0; m < 4; ++m) {
      const int ty = ty0 + 8 * m;
      const int c = c0 + tx, r = r0 + ty;
      const bool adj = adj_eval(s, tx, ty, c, r, thr);
      const bool keep = !(pbits(kd0, kd1, (u32)(r * NPX + c)) >> 31);
      out[(size_t)r * NPX + c] = (adj && keep) ? 1 : 0;
    }
  }
}

// ==================== fallback: verified 2-kernel path ====================
__global__ __launch_bounds__(256) void k_pool(const float* __restrict__ coarse,
                                              float2* __restrict__ dn2,
                                              float* __restrict__ pmin,
                                              float* __restrict__ pmax,
                                              u32 kn0, u32 kn1) {
  const u32 g = blockIdx.x * 256 + threadIdx.x;
  const int i  = g >> 10;
  const int jj = g & 1023;

  const float4* r0 = (const float4*)(coarse + (size_t)(2*i       ) * 4096);
  const float4* r1 = (const float4*)(coarse + (size_t)(2*i + 1   ) * 4096);
  const float4* r2 = (const float4*)(coarse + (size_t)(2*i + 2048) * 4096);
  const float4* r3 = (const float4*)(coarse + (size_t)(2*i + 2049) * 4096);
  const float4 a = r0[jj], b = r1[jj], c = r2[jj], d = r3[jj];

  const float p0a = fmaxf(fmaxf(a.x, a.y), fmaxf(b.x, b.y));
  const float p0b = fmaxf(fmaxf(a.z, a.w), fmaxf(b.z, b.w));
  const float p1a = fmaxf(fmaxf(c.x, c.y), fmaxf(d.x, d.y));
  const float p1b = fmaxf(fmaxf(c.z, c.w), fmaxf(d.z, d.w));

  float lmin = fminf(fminf(p0a, p0b), fminf(p1a, p1b));
  float lmax = fmaxf(fmaxf(p0a, p0b), fmaxf(p1a, p1b));

  const u32 t0 = (u32)i * 2048u + 2u * (u32)jj;
  const u32 t2 = t0 + HALF_T;
  dn2[(size_t)i * 1024 + jj] =
      make_float2(p0a + bits_to_uniform(pbits(kn0, kn1, t0)),
                  p0b + bits_to_uniform(pbits(kn0, kn1, t0 + 1u)));
  dn2[(size_t)(i + 1024) * 1024 + jj] =
      make_float2(p1a + bits_to_uniform(pbits(kn0, kn1, t2)),
                  p1b + bits_to_uniform(pbits(kn0, kn1, t2 + 1u)));

  for (int off = 32; off > 0; off >>= 1) {
    lmin = fminf(lmin, __shfl_down(lmin, off, 64));
    lmax = fmaxf(lmax, __shfl_down(lmax, off, 64));
  }
  __shared__ float smin[4], smax[4];
  const int lane = threadIdx.x & 63, wv = threadIdx.x >> 6;
  if (lane == 0) { smin[wv] = lmin; smax[wv] = lmax; }
  __syncthreads();
  if (threadIdx.x == 0) {
    pmin[blockIdx.x] = fminf(fminf(smin[0], smin[1]), fminf(smin[2], smin[3]));
    pmax[blockIdx.x] = fmaxf(fmaxf(smax[0], smax[1]), fmaxf(smax[2], smax[3]));
  }
}

__device__ inline float block_thr(const float* __restrict__ pmin,
                                  const float* __restrict__ pmax,
                                  int tid) {
  __shared__ float smin[16], smax[16], sthr;
  float lmin = INFINITY, lmax = -INFINITY;
#pragma unroll
  for (int k = 0; k < NPOOL_BLOCKS; k += 1024) {
    lmin = fminf(lmin, pmin[tid + k]);
    lmax = fmaxf(lmax, pmax[tid + k]);
  }
  for (int off = 32; off > 0; off >>= 1) {
    lmin = fminf(lmin, __shfl_down(lmin, off, 64));
    lmax = fmaxf(lmax, __shfl_down(lmax, off, 64));
  }
  const int lane = tid & 63, wv = tid >> 6;
  if (lane == 0) { smin[wv] = lmin; smax[wv] = lmax; }
  __syncthreads();
  if (tid == 0) {
    float gmin = smin[0], gmax = smax[0];
#pragma unroll
    for (int w = 1; w < 16; ++w) {
      gmin = fminf(gmin, smin[w]);
      gmax = fmaxf(gmax, smax[w]);
    }
    sthr = (gmax - gmin) / 2048.0f;
  }
  __syncthreads();
  return sthr;
}

__global__ __launch_bounds__(1024) void k_graph(const float* __restrict__ dn,
                                                const float* __restrict__ pmin,
                                                const float* __restrict__ pmax,
                                                int* __restrict__ out,
                                                u32 kd0, u32 kd1) {
  __shared__ float s0[34][35];
  __shared__ float s1[34][35];
  const int tid = threadIdx.y * 32 + threadIdx.x;
  const float thr = block_thr(pmin, pmax, tid);

  const int c0 = blockIdx.x * 32, r0 = blockIdx.y * 32;
  for (int idx = tid; idx < 34 * 34; idx += 1024) {
    const int lc = idx / 34, lr = idx - lc * 34;
    const int c = c0 - 1 + lc;
    const int r = r0 - 1 + lr;
    float v0 = 0.f, v1 = 0.f;
    if ((unsigned)c < (unsigned)NPX) {
      if ((unsigned)r < (unsigned)NPX)          v0 = dn[c * NPX + r];
      const int r2 = r + 1024;
      if ((unsigned)r2 < (unsigned)NPX)         v1 = dn[c * NPX + r2];
    }
    s0[lc][lr] = v0;
    s1[lc][lr] = v1;
  }
  __syncthreads();
  const int tx = threadIdx.x, ty = threadIdx.y;
  const int c = c0 + tx, r = r0 + ty;
  const bool adj0 = adj_eval(s0, tx, ty, c, r,        thr);
  const bool adj1 = adj_eval(s1, tx, ty, c, r + 1024, thr);
  const u32 t0 = (u32)(r * NPX + c);
  const bool keep0 = !(pbits(kd0, kd1, t0)          >> 31);
  const bool keep1 = !(pbits(kd0, kd1, t0 + HALF_T) >> 31);
  out[(size_t)r * NPX + c]          = (adj0 && keep0) ? 1 : 0;
  out[(size_t)(r + 1024) * NPX + c] = (adj1 && keep1) ? 1 : 0;
}

// ---------------- launch ----------------
extern "C" void kernel_launch(void* const* d_in, const int* in_sizes, int n_in,
                              void* d_out, int out_size, void* d_ws, size_t ws_size,
                              hipStream_t stream) {
  const float* coarse = (const float*)d_in[0];
  int* out = (int*)d_out;

  u32 a0 = 0u, a1 = 0u; tf2x32(0u, 1u, a0, a1);   // k_noise = tf(key, (0,0))
  u32 b0 = 0u, b1 = 1u; tf2x32(0u, 1u, b0, b1);   // k_drop  = tf(key, (0,1))
  u32 kn0 = a0, kn1 = a1, kd0 = b0, kd1 = b1;

  char* ws = (char*)d_ws;
  float* pmin = (float*)ws;                       // partials
  float* pmax = (float*)(ws + 16384);
  const size_t dn_off = 32768;
  const size_t dn_bytes = (size_t)NPX * NPX * sizeof(float);
  const bool stored = ws_size >= dn_off + dn_bytes;

  if (stored) {
    float* dn = (float*)(ws + dn_off);
    float2* dn2 = (float2*)dn;
    void* args[] = {(void*)&coarse, (void*)&dn2, (void*)&pmin, (void*)&pmax,
                    (void*)&out, (void*)&kn0, (void*)&kn1, (void*)&kd0, (void*)&kd1};
    hipError_t e = hipLaunchCooperativeKernel((const void*)k_all,
                                              dim3(COOP_BLOCKS), dim3(256),
                                              args, 0, stream);
    if (e == hipSuccess) return;
    // fallback: verified 2-kernel path
    k_pool<<<NPOOL_BLOCKS, 256, 0, stream>>>(coarse, dn2, pmin, pmax, kn0, kn1);
    k_graph<<<dim3(64, 32), dim3(32, 32), 0, stream>>>(dn, pmin, pmax, out, kd0, kd1);
  } else {
    // ws too small: should not happen (harness provides 256 MiB); use 2-kernel path
    // with dn aliased into out? Not possible -- fall back to storing dn in out is
    // incorrect; instead run the stored path only if space allows. Minimal-safe:
    float* dn = (float*)(ws + dn_off);
    k_pool<<<NPOOL_BLOCKS, 256, 0, stream>>>(coarse, (float2*)dn, pmin, pmax, kn0, kn1);
    k_graph<<<dim3(64, 32), dim3(32, 32), 0, stream>>>(dn, pmin, pmax, out, kd0, kd1);
  }
}

// Round 4
// 116.246 us; speedup vs baseline: 2.0550x; 2.0550x over previous
//
#include <hip/hip_runtime.h>

typedef unsigned int u32;

#define HALF_T 2097152u   // 2048*2048/2
#define NPX 2048
#define NPOOL_BLOCKS 4096

// ---------------- threefry2x32 (JAX-exact, 20 rounds) ----------------
__host__ __device__ inline void tf2x32(u32 k0, u32 k1, u32& x0, u32& x1) {
  const u32 ks2 = k0 ^ k1 ^ 0x1BD11BDAu;
  x0 += k0; x1 += k1;
#define TFR(r) { x0 += x1; x1 = (x1 << (r)) | (x1 >> (32 - (r))); x1 ^= x0; }
  TFR(13) TFR(15) TFR(26) TFR(6)
  x0 += k1;  x1 += ks2 + 1u;
  TFR(17) TFR(29) TFR(16) TFR(24)
  x0 += ks2; x1 += k0 + 2u;
  TFR(13) TFR(15) TFR(26) TFR(6)
  x0 += k0;  x1 += k1 + 3u;
  TFR(17) TFR(29) TFR(16) TFR(24)
  x0 += k1;  x1 += ks2 + 4u;
  TFR(13) TFR(15) TFR(26) TFR(6)
  x0 += ks2; x1 += k0 + 5u;
#undef TFR
}

// Partitionable-threefry random bits for flat index t (size < 2^32 -> hi word 0):
// bits[t] = x0 ^ x1 of threefry2x32(key, (0, t)).
__device__ inline u32 pbits(u32 k0, u32 k1, u32 t) {
  u32 x0 = 0u, x1 = t;
  tf2x32(k0, k1, x0, x1);
  return x0 ^ x1;
}

__device__ inline float bits_to_uniform(u32 bits) {
  return __uint_as_float((bits >> 9) | 0x3F800000u) - 1.0f;
}

// -------- kernel 1: maxpool + noise + store dn (float2) + partial min/max --------
// 4096 blocks x 256 threads; thread g handles pool rows (i, i+1024), cols (2jj, 2jj+1).
__global__ __launch_bounds__(256) void k_pool(const float* __restrict__ coarse,
                                              float2* __restrict__ dn2,
                                              float* __restrict__ pmin,
                                              float* __restrict__ pmax,
                                              u32 kn0, u32 kn1) {
  const u32 g = blockIdx.x * 256 + threadIdx.x;   // [0, 1048576)
  const int i  = g >> 10;                         // pool row in [0,1024)
  const int jj = g & 1023;                        // float4 col index

  const float4* r0 = (const float4*)(coarse + (size_t)(2*i       ) * 4096);
  const float4* r1 = (const float4*)(coarse + (size_t)(2*i + 1   ) * 4096);
  const float4* r2 = (const float4*)(coarse + (size_t)(2*i + 2048) * 4096);
  const float4* r3 = (const float4*)(coarse + (size_t)(2*i + 2049) * 4096);
  const float4 a = r0[jj], b = r1[jj], c = r2[jj], d = r3[jj];

  const float p0a = fmaxf(fmaxf(a.x, a.y), fmaxf(b.x, b.y));
  const float p0b = fmaxf(fmaxf(a.z, a.w), fmaxf(b.z, b.w));
  const float p1a = fmaxf(fmaxf(c.x, c.y), fmaxf(d.x, d.y));
  const float p1b = fmaxf(fmaxf(c.z, c.w), fmaxf(d.z, d.w));

  float lmin = fminf(fminf(p0a, p0b), fminf(p1a, p1b));
  float lmax = fmaxf(fmaxf(p0a, p0b), fmaxf(p1a, p1b));

  const u32 t0 = (u32)i * 2048u + 2u * (u32)jj;
  const u32 t2 = t0 + HALF_T;
  dn2[(size_t)i * 1024 + jj] =
      make_float2(p0a + bits_to_uniform(pbits(kn0, kn1, t0)),
                  p0b + bits_to_uniform(pbits(kn0, kn1, t0 + 1u)));
  dn2[(size_t)(i + 1024) * 1024 + jj] =
      make_float2(p1a + bits_to_uniform(pbits(kn0, kn1, t2)),
                  p1b + bits_to_uniform(pbits(kn0, kn1, t2 + 1u)));

  // wave (64) reduce, then block reduce
  for (int off = 32; off > 0; off >>= 1) {
    lmin = fminf(lmin, __shfl_down(lmin, off, 64));
    lmax = fmaxf(lmax, __shfl_down(lmax, off, 64));
  }
  __shared__ float smin[4], smax[4];
  const int lane = threadIdx.x & 63, wv = threadIdx.x >> 6;
  if (lane == 0) { smin[wv] = lmin; smax[wv] = lmax; }
  __syncthreads();
  if (threadIdx.x == 0) {
    pmin[blockIdx.x] = fminf(fminf(smin[0], smin[1]), fminf(smin[2], smin[3]));
    pmax[blockIdx.x] = fmaxf(fmaxf(smax[0], smax[1]), fmaxf(smax[2], smax[3]));
  }
}

// -------- per-block redundant final reduce (partials sit in L2) --------
__device__ inline float block_thr(const float* __restrict__ pmin,
                                  const float* __restrict__ pmax,
                                  int tid) {
  __shared__ float smin[16], smax[16], sthr;
  float lmin = INFINITY, lmax = -INFINITY;
#pragma unroll
  for (int k = 0; k < NPOOL_BLOCKS; k += 1024) {
    lmin = fminf(lmin, pmin[tid + k]);
    lmax = fmaxf(lmax, pmax[tid + k]);
  }
  for (int off = 32; off > 0; off >>= 1) {
    lmin = fminf(lmin, __shfl_down(lmin, off, 64));
    lmax = fmaxf(lmax, __shfl_down(lmax, off, 64));
  }
  const int lane = tid & 63, wv = tid >> 6;
  if (lane == 0) { smin[wv] = lmin; smax[wv] = lmax; }
  __syncthreads();
  if (tid == 0) {
    float gmin = smin[0], gmax = smax[0];
#pragma unroll
    for (int w = 1; w < 16; ++w) {
      gmin = fminf(gmin, smin[w]);
      gmax = fmaxf(gmax, smax[w]);
    }
    sthr = (gmax - gmin) / 2048.0f;
  }
  __syncthreads();
  return sthr;
}

// -------- adjacency evaluation from an LDS tile --------
// s[lc][lr] = dn[i = cbase-1+lc][j = rbase-1+lr]; thread center at lc=tx+1, lr=ty+1.
__device__ inline bool adj_eval(const float s[34][35], int tx, int ty,
                                int c, int rr, float thr) {
  const float ctr = s[tx+1][ty+1];
  const bool cge1 = (c  >= 1),    cle = (c  <= NPX - 2);
  const bool rge1 = (rr >= 1),    rle = (rr <= NPX - 2);
  bool a = false;
  if (cge1 && rge1)                    a |= (fabsf(s[tx  ][ty  ] - ctr) <= thr); // d[i-1,j-1]
  if (cge1 && cle && rge1 && rle)      a |= (fabsf(s[tx+2][ty  ] - ctr) <= thr); // d[i+1,j-1]
  if (cge1 && rle)                     a |= (fabsf(s[tx  ][ty+2] - ctr) <= thr); // d[i-1,j+1]
  if (cle  && rle)                     a |= (fabsf(s[tx+2][ty+2] - ctr) <= thr); // d[i+1,j+1]
  return a;
}

// -------- kernel 2: thr reduce + adjacency + dropout; OUTPUT IS INT32 --------
__global__ __launch_bounds__(1024) void k_graph(const float* __restrict__ dn,
                                                const float* __restrict__ pmin,
                                                const float* __restrict__ pmax,
                                                int* __restrict__ out,
                                                u32 kd0, u32 kd1) {
  __shared__ float s0[34][35];
  __shared__ float s1[34][35];
  const int tid = threadIdx.y * 32 + threadIdx.x;
  const float thr = block_thr(pmin, pmax, tid);

  const int c0 = blockIdx.x * 32, r0 = blockIdx.y * 32;
  for (int idx = tid; idx < 34 * 34; idx += 1024) {
    const int lc = idx / 34, lr = idx - lc * 34;
    const int c = c0 - 1 + lc;        // dn row index (i)
    const int r = r0 - 1 + lr;        // dn col index (j), tile0
    float v0 = 0.f, v1 = 0.f;
    if ((unsigned)c < (unsigned)NPX) {
      if ((unsigned)r < (unsigned)NPX)          v0 = dn[c * NPX + r];
      const int r2 = r + 1024;
      if ((unsigned)r2 < (unsigned)NPX)         v1 = dn[c * NPX + r2];
    }
    s0[lc][lr] = v0;
    s1[lc][lr] = v1;
  }
  __syncthreads();
  const int tx = threadIdx.x, ty = threadIdx.y;
  const int c = c0 + tx, r = r0 + ty;          // out col / out row (first tile)
  const bool adj0 = adj_eval(s0, tx, ty, c, r,        thr);
  const bool adj1 = adj_eval(s1, tx, ty, c, r + 1024, thr);
  const u32 t0 = (u32)(r * NPX + c);
  // bernoulli(0.5): uniform < 0.5  <=>  top bit of bits == 0
  const bool keep0 = !(pbits(kd0, kd1, t0)          >> 31);
  const bool keep1 = !(pbits(kd0, kd1, t0 + HALF_T) >> 31);
  out[(size_t)r * NPX + c]          = (adj0 && keep0) ? 1 : 0;
  out[(size_t)(r + 1024) * NPX + c] = (adj1 && keep1) ? 1 : 0;
}

// -------- fallback (ws too small for dn): minmax-only pool + fused recompute --------
__global__ __launch_bounds__(256) void k_pool_nostore(const float* __restrict__ coarse,
                                                      float* __restrict__ pmin,
                                                      float* __restrict__ pmax) {
  const u32 g = blockIdx.x * 256 + threadIdx.x;
  const int i  = g >> 10;
  const int jj = g & 1023;
  const float4* r0 = (const float4*)(coarse + (size_t)(2*i       ) * 4096);
  const float4* r1 = (const float4*)(coarse + (size_t)(2*i + 1   ) * 4096);
  const float4* r2 = (const float4*)(coarse + (size_t)(2*i + 2048) * 4096);
  const float4* r3 = (const float4*)(coarse + (size_t)(2*i + 2049) * 4096);
  const float4 a = r0[jj], b = r1[jj], c = r2[jj], d = r3[jj];
  float lmin = fminf(fminf(fmaxf(fmaxf(a.x,a.y),fmaxf(b.x,b.y)),
                           fmaxf(fmaxf(a.z,a.w),fmaxf(b.z,b.w))),
                     fminf(fmaxf(fmaxf(c.x,c.y),fmaxf(d.x,d.y)),
                           fmaxf(fmaxf(c.z,c.w),fmaxf(d.z,d.w))));
  float lmax = fmaxf(fmaxf(fmaxf(fmaxf(a.x,a.y),fmaxf(b.x,b.y)),
                           fmaxf(fmaxf(a.z,a.w),fmaxf(b.z,b.w))),
                     fmaxf(fmaxf(fmaxf(c.x,c.y),fmaxf(d.x,d.y)),
                           fmaxf(fmaxf(c.z,c.w),fmaxf(d.z,d.w))));
  for (int off = 32; off > 0; off >>= 1) {
    lmin = fminf(lmin, __shfl_down(lmin, off, 64));
    lmax = fmaxf(lmax, __shfl_down(lmax, off, 64));
  }
  __shared__ float smin[4], smax[4];
  const int lane = threadIdx.x & 63, wv = threadIdx.x >> 6;
  if (lane == 0) { smin[wv] = lmin; smax[wv] = lmax; }
  __syncthreads();
  if (threadIdx.x == 0) {
    pmin[blockIdx.x] = fminf(fminf(smin[0], smin[1]), fminf(smin[2], smin[3]));
    pmax[blockIdx.x] = fmaxf(fmaxf(smax[0], smax[1]), fmaxf(smax[2], smax[3]));
  }
}

__device__ inline float dn_compute(const float* __restrict__ coarse,
                                   int i, int j, u32 kn0, u32 kn1) {
  const float2* r0 = (const float2*)(coarse + (size_t)(2*i    ) * 4096);
  const float2* r1 = (const float2*)(coarse + (size_t)(2*i + 1) * 4096);
  float2 a = r0[j], b = r1[j];
  float p = fmaxf(fmaxf(a.x, a.y), fmaxf(b.x, b.y));
  return p + bits_to_uniform(pbits(kn0, kn1, (u32)(i * NPX + j)));
}

__global__ __launch_bounds__(1024) void k_graph_fused(const float* __restrict__ coarse,
                                                      const float* __restrict__ pmin,
                                                      const float* __restrict__ pmax,
                                                      int* __restrict__ out,
                                                      u32 kn0, u32 kn1, u32 kd0, u32 kd1) {
  __shared__ float s0[34][35];
  __shared__ float s1[34][35];
  const int tid = threadIdx.y * 32 + threadIdx.x;
  const float thr = block_thr(pmin, pmax, tid);
  const int c0 = blockIdx.x * 32, r0 = blockIdx.y * 32;
  for (int idx = tid; idx < 34 * 34; idx += 1024) {
    const int lc = idx / 34, lr = idx - lc * 34;
    const int c = c0 - 1 + lc;
    const int r = r0 - 1 + lr;
    float v0 = 0.f, v1 = 0.f;
    if ((unsigned)c < (unsigned)NPX) {
      if ((unsigned)r < (unsigned)NPX)      v0 = dn_compute(coarse, c, r, kn0, kn1);
      const int r2 = r + 1024;
      if ((unsigned)r2 < (unsigned)NPX)     v1 = dn_compute(coarse, c, r2, kn0, kn1);
    }
    s0[lc][lr] = v0;
    s1[lc][lr] = v1;
  }
  __syncthreads();
  const int tx = threadIdx.x, ty = threadIdx.y;
  const int c = c0 + tx, r = r0 + ty;
  const bool adj0 = adj_eval(s0, tx, ty, c, r,        thr);
  const bool adj1 = adj_eval(s1, tx, ty, c, r + 1024, thr);
  const u32 t0 = (u32)(r * NPX + c);
  const bool keep0 = !(pbits(kd0, kd1, t0)          >> 31);
  const bool keep1 = !(pbits(kd0, kd1, t0 + HALF_T) >> 31);
  out[(size_t)r * NPX + c]          = (adj0 && keep0) ? 1 : 0;
  out[(size_t)(r + 1024) * NPX + c] = (adj1 && keep1) ? 1 : 0;
}

// ---------------- launch ----------------
extern "C" void kernel_launch(void* const* d_in, const int* in_sizes, int n_in,
                              void* d_out, int out_size, void* d_ws, size_t ws_size,
                              hipStream_t stream) {
  const float* coarse = (const float*)d_in[0];
  int* out = (int*)d_out;

  // jax.random.split under threefry_partitionable (modern default), "foldlike":
  // keys[i] = full output pair of threefry2x32(key=(0,1), counts=(hi=0, lo=i)).
  u32 a0 = 0u, a1 = 0u; tf2x32(0u, 1u, a0, a1);   // k_noise = tf(key, (0,0))
  u32 b0 = 0u, b1 = 1u; tf2x32(0u, 1u, b0, b1);   // k_drop  = tf(key, (0,1))
  const u32 kn0 = a0, kn1 = a1, kd0 = b0, kd1 = b1;

  char* ws = (char*)d_ws;
  float* pmin = (float*)ws;                       // 4096 floats
  float* pmax = (float*)(ws + 16384);             // 4096 floats
  const size_t dn_off = 32768;
  const size_t dn_bytes = (size_t)NPX * NPX * sizeof(float);
  const bool stored = ws_size >= dn_off + dn_bytes;

  if (stored) {
    float* dn = (float*)(ws + dn_off);
    k_pool<<<NPOOL_BLOCKS, 256, 0, stream>>>(coarse, (float2*)dn, pmin, pmax, kn0, kn1);
    k_graph<<<dim3(64, 32), dim3(32, 32), 0, stream>>>(dn, pmin, pmax, out, kd0, kd1);
  } else {
    k_pool_nostore<<<NPOOL_BLOCKS, 256, 0, stream>>>(coarse, pmin, pmax);
    k_graph_fused<<<dim3(64, 32), dim3(32, 32), 0, stream>>>(coarse, pmin, pmax, out,
                                                             kn0, kn1, kd0, kd1);
  }
}